// Round 1
// baseline (3679.272 us; speedup 1.0000x reference)
//
#include <hip/hip_runtime.h>
#include <cstdint>
#include <cstddef>

// Problem: qkv = hidden[16384,4096] @ W^T, W=[12288,4096] (B^T GEMM),
// split into q/k/v contiguous [16384,4096] fp32 blocks.
#define M_DIM 16384
#define K_DIM 4096
#define N_DIM 12288
#define BM 128
#define BN 128
#define BK 32

typedef __bf16 bf16x8 __attribute__((ext_vector_type(8)));
typedef float floatx4 __attribute__((ext_vector_type(4)));

__device__ __forceinline__ unsigned short f2bf(float f) {
  union { float f; unsigned int u; } v; v.f = f;
  unsigned int u = v.u;
  unsigned int r = (u + 0x7FFFu + ((u >> 16) & 1u)) >> 16;  // RNE
  return (unsigned short)r;
}

__global__ __launch_bounds__(256) void cvt_f32_bf16(const float* __restrict__ src,
                                                    unsigned short* __restrict__ dst,
                                                    int n4) {
  int i = blockIdx.x * blockDim.x + threadIdx.x;
  if (i >= n4) return;
  const float4 f = reinterpret_cast<const float4*>(src)[i];
  ushort4 o;
  o.x = f2bf(f.x); o.y = f2bf(f.y); o.z = f2bf(f.z); o.w = f2bf(f.w);
  reinterpret_cast<ushort4*>(dst)[i] = o;
}

// async global->LDS, 16B per lane. LDS dest is wave-uniform base + lane*16.
__device__ __forceinline__ void async_copy16(const unsigned short* g, unsigned short* l) {
  __builtin_amdgcn_global_load_lds(
      (const __attribute__((address_space(1))) unsigned int*)g,
      (__attribute__((address_space(3))) unsigned int*)l,
      16, 0, 0);
}

// m97-pattern GEMM: C[m][n] = sum_k A[m][k]*W[n][k], bf16 in, fp32 out.
// Output scatter: out[(n>>12)*M*4096 + m*4096 + (n&4095)].
__global__ __launch_bounds__(256) void gemm_qkv_bf16(const unsigned short* __restrict__ A,
                                                     const unsigned short* __restrict__ W,
                                                     float* __restrict__ out) {
  __shared__ __align__(16) unsigned short As[BM * BK];  // 8 KB
  __shared__ __align__(16) unsigned short Bs[BN * BK];  // 8 KB

  const int tid  = threadIdx.x;
  const int w    = tid >> 6;     // wave 0..3
  const int lane = tid & 63;
  const int bm = blockIdx.x & 127;   // M/BM = 128
  const int bn = blockIdx.x >> 7;    // N/BN = 96

  const int rowA0 = bm * BM;
  const int rowB0 = bn * BN;

  // Staging map: tile is [128 rows][32 bf16] row-major (64 B/row, 8192 B).
  // Wave w, instr j covers bytes [w*2048 + j*1024, +1024); lane L -> +L*16.
  const int oA0 = w * 2048 + lane * 16;
  const int oA1 = oA0 + 1024;
  const unsigned short* gA0 = A + (size_t)(rowA0 + (oA0 >> 6)) * K_DIM + ((oA0 & 63) >> 1);
  const unsigned short* gA1 = A + (size_t)(rowA0 + (oA1 >> 6)) * K_DIM + ((oA1 & 63) >> 1);
  const unsigned short* gB0 = W + (size_t)(rowB0 + (oA0 >> 6)) * K_DIM + ((oA0 & 63) >> 1);
  const unsigned short* gB1 = W + (size_t)(rowB0 + (oA1 >> 6)) * K_DIM + ((oA1 & 63) >> 1);
  unsigned short* lA0 = &As[(w * 2048) >> 1];           // wave-uniform bases
  unsigned short* lA1 = &As[(w * 2048 + 1024) >> 1];
  unsigned short* lB0 = &Bs[(w * 2048) >> 1];
  unsigned short* lB1 = &Bs[(w * 2048 + 1024) >> 1];

  const int quad = lane >> 4;
  const int lrow = lane & 15;
  const int wm = (w >> 1) * 64;
  const int wn = (w & 1) * 64;

  floatx4 acc[4][4];
  const floatx4 zero = {0.f, 0.f, 0.f, 0.f};
#pragma unroll
  for (int i = 0; i < 4; ++i)
#pragma unroll
    for (int j = 0; j < 4; ++j) acc[i][j] = zero;

  for (int k0 = 0; k0 < K_DIM; k0 += BK) {
    async_copy16(gA0 + k0, lA0);
    async_copy16(gA1 + k0, lA1);
    async_copy16(gB0 + k0, lB0);
    async_copy16(gB1 + k0, lB1);
    __syncthreads();  // drains vmcnt(0): staging complete

    bf16x8 a[4], b[4];
#pragma unroll
    for (int t = 0; t < 4; ++t) {
      a[t] = *reinterpret_cast<const bf16x8*>(&As[(wm + t * 16 + lrow) * BK + quad * 8]);
      b[t] = *reinterpret_cast<const bf16x8*>(&Bs[(wn + t * 16 + lrow) * BK + quad * 8]);
    }
#pragma unroll
    for (int ti = 0; ti < 4; ++ti)
#pragma unroll
      for (int tj = 0; tj < 4; ++tj)
        acc[ti][tj] = __builtin_amdgcn_mfma_f32_16x16x32_bf16(a[ti], b[tj], acc[ti][tj], 0, 0, 0);
    __syncthreads();  // protect LDS before next stage
  }

  // Epilogue. C/D layout: col = lane&15, row = quad*4 + reg.
  const int rBase = rowA0 + wm + quad * 4;
  const int cBase = rowB0 + wn + lrow;
#pragma unroll
  for (int ti = 0; ti < 4; ++ti) {
#pragma unroll
    for (int tj = 0; tj < 4; ++tj) {
      const int c = cBase + tj * 16;
      const int which = c >> 12;  // q/k/v selector (block-uniform since 128 | 4096)
      float* o = out + ((size_t)which * M_DIM + (rBase + ti * 16)) * 4096 + (c & 4095);
#pragma unroll
      for (int i = 0; i < 4; ++i) o[(size_t)i * 4096] = acc[ti][tj][i];
    }
  }
}

// Fallback (only if ws too small): convert fp32->bf16 during LDS staging.
__global__ __launch_bounds__(256) void gemm_qkv_f32(const float* __restrict__ A,
                                                    const float* __restrict__ W,
                                                    float* __restrict__ out) {
  __shared__ __align__(16) unsigned short As[BM * BK];
  __shared__ __align__(16) unsigned short Bs[BN * BK];
  const int tid  = threadIdx.x;
  const int w    = tid >> 6;
  const int lane = tid & 63;
  const int bm = blockIdx.x & 127;
  const int bn = blockIdx.x >> 7;
  const int rowA0 = bm * BM;
  const int rowB0 = bn * BN;
  const int sRow = tid >> 1;          // 0..127
  const int sK   = (tid & 1) * 16;    // 0 or 16
  const float* gA = A + (size_t)(rowA0 + sRow) * K_DIM + sK;
  const float* gB = W + (size_t)(rowB0 + sRow) * K_DIM + sK;
  unsigned short* sA = &As[sRow * BK + sK];
  unsigned short* sB = &Bs[sRow * BK + sK];

  const int quad = lane >> 4;
  const int lrow = lane & 15;
  const int wm = (w >> 1) * 64;
  const int wn = (w & 1) * 64;

  floatx4 acc[4][4];
  const floatx4 zero = {0.f, 0.f, 0.f, 0.f};
#pragma unroll
  for (int i = 0; i < 4; ++i)
#pragma unroll
    for (int j = 0; j < 4; ++j) acc[i][j] = zero;

  for (int k0 = 0; k0 < K_DIM; k0 += BK) {
#pragma unroll
    for (int j = 0; j < 4; ++j) {
      float4 fa = *reinterpret_cast<const float4*>(gA + k0 + j * 4);
      float4 fb = *reinterpret_cast<const float4*>(gB + k0 + j * 4);
      ushort4 ua, ub;
      ua.x = f2bf(fa.x); ua.y = f2bf(fa.y); ua.z = f2bf(fa.z); ua.w = f2bf(fa.w);
      ub.x = f2bf(fb.x); ub.y = f2bf(fb.y); ub.z = f2bf(fb.z); ub.w = f2bf(fb.w);
      *reinterpret_cast<ushort4*>(sA + j * 4) = ua;
      *reinterpret_cast<ushort4*>(sB + j * 4) = ub;
    }
    __syncthreads();

    bf16x8 a[4], b[4];
#pragma unroll
    for (int t = 0; t < 4; ++t) {
      a[t] = *reinterpret_cast<const bf16x8*>(&As[(wm + t * 16 + lrow) * BK + quad * 8]);
      b[t] = *reinterpret_cast<const bf16x8*>(&Bs[(wn + t * 16 + lrow) * BK + quad * 8]);
    }
#pragma unroll
    for (int ti = 0; ti < 4; ++ti)
#pragma unroll
      for (int tj = 0; tj < 4; ++tj)
        acc[ti][tj] = __builtin_amdgcn_mfma_f32_16x16x32_bf16(a[ti], b[tj], acc[ti][tj], 0, 0, 0);
    __syncthreads();
  }

  const int rBase = rowA0 + wm + quad * 4;
  const int cBase = rowB0 + wn + lrow;
#pragma unroll
  for (int ti = 0; ti < 4; ++ti) {
#pragma unroll
    for (int tj = 0; tj < 4; ++tj) {
      const int c = cBase + tj * 16;
      const int which = c >> 12;
      float* o = out + ((size_t)which * M_DIM + (rBase + ti * 16)) * 4096 + (c & 4095);
#pragma unroll
      for (int i = 0; i < 4; ++i) o[(size_t)i * 4096] = acc[ti][tj][i];
    }
  }
}

extern "C" void kernel_launch(void* const* d_in, const int* in_sizes, int n_in,
                              void* d_out, int out_size, void* d_ws, size_t ws_size,
                              hipStream_t stream) {
  const float* hidden = (const float*)d_in[0];   // [4,4096,4096] fp32
  const float* qkvw   = (const float*)d_in[1];   // [12288,4096] fp32
  // d_in[2] = position_ids: unused (RoPE is identity stub)
  float* out = (float*)d_out;                    // 3 * [16384,4096] fp32

  const size_t elemsA = (size_t)M_DIM * K_DIM;   // 67,108,864
  const size_t elemsW = (size_t)N_DIM * K_DIM;   // 50,331,648
  const size_t need   = (elemsA + elemsW) * sizeof(unsigned short);  // 224 MiB

  const int grid = (M_DIM / BM) * (N_DIM / BN);  // 128 * 96 = 12288 blocks

  if (ws_size >= need) {
    unsigned short* A_bf = (unsigned short*)d_ws;
    unsigned short* W_bf = A_bf + elemsA;
    cvt_f32_bf16<<<(int)(elemsA / 4 / 256), 256, 0, stream>>>(hidden, A_bf, (int)(elemsA / 4));
    cvt_f32_bf16<<<(int)(elemsW / 4 / 256), 256, 0, stream>>>(qkvw,   W_bf, (int)(elemsW / 4));
    gemm_qkv_bf16<<<grid, 256, 0, stream>>>(A_bf, W_bf, out);
  } else {
    gemm_qkv_f32<<<grid, 256, 0, stream>>>(hidden, qkvw, out);
  }
}